// Round 1
// baseline (191.943 us; speedup 1.0000x reference)
//
#include <hip/hip_runtime.h>

typedef _Float16 f16;
typedef _Float16 f16x2 __attribute__((ext_vector_type(2)));
typedef _Float16 f16x8 __attribute__((ext_vector_type(8)));
typedef float    f32x4 __attribute__((ext_vector_type(4)));

#define DIM 128

// silu(x) = x / (1 + e^-x); v_exp_f32 is 2^x so scale by log2(e). v_rcp_f32 ~1ulp.
__device__ __forceinline__ float silu_f(float x) {
    float e = __builtin_amdgcn_exp2f(x * -1.44269504088896341f);
    return x * __builtin_amdgcn_rcpf(1.0f + e);
}

// Block = 256 threads = 4 waves. Each wave owns 16 rows per tile; block tile = 64 rows.
// LDS: W1,W2 in mfma_f32_16x16x32_f16 B-frag layout (fp16, 32KB each) + per-wave
// x1 staging (16KB, XOR-swizzled 16B chunks) = 80KB -> 2 blocks/CU.
__global__ __launch_bounds__(256, 2)
void ts_mlp_kernel(const float* __restrict__ t,
                   const float* __restrict__ W1, const float* __restrict__ b1,
                   const float* __restrict__ W2, const float* __restrict__ b2,
                   float* __restrict__ out, int B) {
    // B-frag layout: frag for (kt, nt) in lane L holds B[k][n] with
    //   n = nt*16 + (L&15), k = kt*32 + (L>>4)*8 + j, j=0..7  (= W[n][k], 8 consecutive k)
    __shared__ f16x8 w1f[4][8][64];
    __shared__ f16x8 w2f[4][8][64];
    // x1 staging, per wave: 16 rows x 128 k as 16B chunks; chunk (m, c=k>>3) lives at
    // physical chunk m*16 + (c ^ m)  -> conflict-free (<=2-way) reads and writes.
    __shared__ f16x2 x1p[4][256][4];

    const int tid  = threadIdx.x;
    const int wv   = tid >> 6;
    const int lane = tid & 63;
    const int q    = lane >> 4;   // quad index 0..3
    const int ln   = lane & 15;
    const int par  = lane & 1;

    // ---- prologue: stage W1/W2 -> LDS fp16 fragments (each lane: 32B contiguous rows)
    for (int mtx = 0; mtx < 2; ++mtx) {
        const float* W = mtx ? W2 : W1;
        for (int nti = 0; nti < 2; ++nti) {
            const int nt = wv * 2 + nti;
            const int n  = nt * 16 + ln;
            for (int kt = 0; kt < 4; ++kt) {
                const int k0 = kt * 32 + q * 8;
                const float4* src = (const float4*)(W + n * DIM + k0);
                float4 lo = src[0], hi = src[1];
                f16x8 fr;
                fr[0] = (f16)lo.x; fr[1] = (f16)lo.y; fr[2] = (f16)lo.z; fr[3] = (f16)lo.w;
                fr[4] = (f16)hi.x; fr[5] = (f16)hi.y; fr[6] = (f16)hi.z; fr[7] = (f16)hi.w;
                if (mtx) w2f[kt][nt][lane] = fr; else w1f[kt][nt][lane] = fr;
            }
        }
    }
    float b1v[8], b2v[8];
#pragma unroll
    for (int nt = 0; nt < 8; ++nt) {
        b1v[nt] = b1[nt * 16 + ln];
        b2v[nt] = b2[nt * 16 + ln];
    }
    __syncthreads();

    const int ntiles = B >> 6;
    for (int tile = blockIdx.x; tile < ntiles; tile += gridDim.x) {
        const int row0 = tile * 64 + wv * 16;

        // ---- emb directly in A-frag layout: row m = ln, k = kt*32 + q*8 + j
        // v_sin/v_cos take REVOLUTIONS: phase_d * t / 2pi = d*t/256
        const float tv   = t[row0 + ln];
        const float t256 = tv * 0.00390625f;
        const float o256 = (1.0f - tv) * 0.00390625f;
        f16x8 af[4];
#pragma unroll
        for (int kt = 0; kt < 4; ++kt) {
#pragma unroll
            for (int j = 0; j < 8; ++j) {
                const float fd = (float)(kt * 32 + q * 8 + j);
                const float c  = __builtin_amdgcn_cosf(fd * t256);
                const float s  = __builtin_amdgcn_sinf(fd * o256);
                af[kt][j] = (f16)(tv * (c + s));
            }
        }

        // ---- layer 1: 32 MFMAs
        f32x4 acc[8];
#pragma unroll
        for (int nt = 0; nt < 8; ++nt) acc[nt] = (f32x4){0.f, 0.f, 0.f, 0.f};
#pragma unroll
        for (int kt = 0; kt < 4; ++kt) {
#pragma unroll
            for (int nt = 0; nt < 8; ++nt) {
                acc[nt] = __builtin_amdgcn_mfma_f32_16x16x32_f16(
                    af[kt], w1f[kt][nt][lane], acc[nt], 0, 0, 0);
            }
        }

        // ---- epilogue 1: bias + silu, pack col-pairs cross-lane, write x1 (fp16) to LDS
        // C layout: value r in lane L is x1[row = q*4 + r][col = nt*16 + ln]
#pragma unroll
        for (int nt = 0; nt < 8; ++nt) {
            float v[4], pv[4];
#pragma unroll
            for (int r = 0; r < 4; ++r) v[r] = silu_f(acc[nt][r] + b1v[nt]);
#pragma unroll
            for (int r = 0; r < 4; ++r) pv[r] = __shfl_xor(v[r], 1, 64);
            const int k0  = nt * 16 + (ln & 14);   // even column of the pair
            const int cch = k0 >> 3;               // 16B chunk index
            const int hw  = (k0 & 7) >> 1;         // dword within chunk
#pragma unroll
            for (int p = 0; p < 2; ++p) {
                const int r = par * 2 + p;         // even lanes write rows r=0,1; odd r=2,3
                const int m = q * 4 + r;
                const float lo = par ? pv[r] : v[r];
                const float hi = par ? v[r] : pv[r];
                f16x2 h; h.x = (f16)lo; h.y = (f16)hi;
                x1p[wv][m * 16 + (cch ^ m)][hw] = h;
            }
        }
        // x1p slice is private to this wave; same-wave DS ops are in-order -> no barrier.

        // ---- layer 2: A-frags from LDS, 32 MFMAs
        f32x4 acc2[8];
#pragma unroll
        for (int nt = 0; nt < 8; ++nt) acc2[nt] = (f32x4){0.f, 0.f, 0.f, 0.f};
#pragma unroll
        for (int kt = 0; kt < 4; ++kt) {
            const f16x8 a2 = *(const f16x8*)&x1p[wv][ln * 16 + ((kt * 4 + q) ^ ln)][0];
#pragma unroll
            for (int nt = 0; nt < 8; ++nt) {
                acc2[nt] = __builtin_amdgcn_mfma_f32_16x16x32_f16(
                    a2, w2f[kt][nt][lane], acc2[nt], 0, 0, 0);
            }
        }

        // ---- epilogue 2: bias + silu, fp32 store
#pragma unroll
        for (int nt = 0; nt < 8; ++nt) {
#pragma unroll
            for (int r = 0; r < 4; ++r) {
                const float o = silu_f(acc2[nt][r] + b2v[nt]);
                out[(size_t)(row0 + q * 4 + r) * DIM + nt * 16 + ln] = o;
            }
        }
    }
}

extern "C" void kernel_launch(void* const* d_in, const int* in_sizes, int n_in,
                              void* d_out, int out_size, void* d_ws, size_t ws_size,
                              hipStream_t stream) {
    const float* t  = (const float*)d_in[0];
    const float* W1 = (const float*)d_in[1];
    const float* b1 = (const float*)d_in[2];
    const float* W2 = (const float*)d_in[3];
    const float* b2 = (const float*)d_in[4];
    float* out = (float*)d_out;
    const int B = in_sizes[0];
    const int ntiles = B >> 6;          // 64 rows per block-tile
    int grid = ntiles < 512 ? ntiles : 512;
    ts_mlp_kernel<<<dim3(grid), dim3(256), 0, stream>>>(t, W1, b1, W2, b2, out, B);
}